// Round 7
// baseline (237.650 us; speedup 1.0000x reference)
//
#include <hip/hip_runtime.h>

#define BB 512
#define TT 512
#define NN 64

__device__ __forceinline__ float readlane_f(float v, int lane) {
    return __int_as_float(__builtin_amdgcn_readlane(__float_as_int(v), lane));
}

// R7: cost model from R1-R6: time ~= instrs/step * ~4.5cyc (single-wave issue
// cadence; R5's 2 independent chains = exactly 2x time; hazard-batching R6
// ~null; E lives in AGPRs -- VGPR_Count 56 explained, zero per-use cost).
// => minimize chain instructions:
//  (a) LINEAR-SPACE recurrence q' = Eem .* (E^T q) * 2^-k, k = exponent(s_0):
//      kills per-step exp/log; normalizer accumulates as INT on SALU (exact),
//      reconstructed once at the end: lognorm = m0 + kcum*ln2 + log(sum q).
//  (b) 32x v_pk_fma_f32 (inline asm) with broadcasts batched into fixed
//      SGPRs s40-s55, consumed as aligned pairs (VOP3P scalar operand).
//      s_nop 4 fences the VALU-writes-q -> v_readlane hazard (R4 lesson).

#define S2(x) #x
#define S1(x) S2(x)
#define RLX(SR, L) "v_readlane_b32 " SR ", %4, " S1(L) "\n\t"

#define SCLOB "s40","s41","s42","s43","s44","s45","s46","s47", \
              "s48","s49","s50","s51","s52","s53","s54","s55"

// group 0: lanes 0..15, accs written (pk_mul) -> no init movs needed
#define GRP0() \
    asm volatile( \
        "s_nop 4\n\t" \
        RLX("s40", 0)  RLX("s41", 1)  RLX("s42", 2)  RLX("s43", 3)  \
        RLX("s44", 4)  RLX("s45", 5)  RLX("s46", 6)  RLX("s47", 7)  \
        RLX("s48", 8)  RLX("s49", 9)  RLX("s50", 10) RLX("s51", 11) \
        RLX("s52", 12) RLX("s53", 13) RLX("s54", 14) RLX("s55", 15) \
        "v_pk_mul_f32 %0, s[40:41], %5\n\t" \
        "v_pk_mul_f32 %1, s[42:43], %6\n\t" \
        "v_pk_mul_f32 %2, s[44:45], %7\n\t" \
        "v_pk_mul_f32 %3, s[46:47], %8\n\t" \
        "v_pk_fma_f32 %0, s[48:49], %9,  %0\n\t" \
        "v_pk_fma_f32 %1, s[50:51], %10, %1\n\t" \
        "v_pk_fma_f32 %2, s[52:53], %11, %2\n\t" \
        "v_pk_fma_f32 %3, s[54:55], %12, %3\n\t" \
        : "=&v"(a0), "=&v"(a1), "=&v"(a2), "=&v"(a3) \
        : "v"(q), \
          "v"(EP[0]), "v"(EP[1]), "v"(EP[2]), "v"(EP[3]), \
          "v"(EP[4]), "v"(EP[5]), "v"(EP[6]), "v"(EP[7]) \
        : SCLOB);

// groups 1..3: lanes 16G..16G+15, accumulate
#define GRPN(G) \
    asm volatile( \
        RLX("s40", (G)*16+0)  RLX("s41", (G)*16+1)  RLX("s42", (G)*16+2)  RLX("s43", (G)*16+3)  \
        RLX("s44", (G)*16+4)  RLX("s45", (G)*16+5)  RLX("s46", (G)*16+6)  RLX("s47", (G)*16+7)  \
        RLX("s48", (G)*16+8)  RLX("s49", (G)*16+9)  RLX("s50", (G)*16+10) RLX("s51", (G)*16+11) \
        RLX("s52", (G)*16+12) RLX("s53", (G)*16+13) RLX("s54", (G)*16+14) RLX("s55", (G)*16+15) \
        "v_pk_fma_f32 %0, s[40:41], %5,  %0\n\t" \
        "v_pk_fma_f32 %1, s[42:43], %6,  %1\n\t" \
        "v_pk_fma_f32 %2, s[44:45], %7,  %2\n\t" \
        "v_pk_fma_f32 %3, s[46:47], %8,  %3\n\t" \
        "v_pk_fma_f32 %0, s[48:49], %9,  %0\n\t" \
        "v_pk_fma_f32 %1, s[50:51], %10, %1\n\t" \
        "v_pk_fma_f32 %2, s[52:53], %11, %2\n\t" \
        "v_pk_fma_f32 %3, s[54:55], %12, %3\n\t" \
        : "+v"(a0), "+v"(a1), "+v"(a2), "+v"(a3) \
        : "v"(q), \
          "v"(EP[8*(G)+0]), "v"(EP[8*(G)+1]), "v"(EP[8*(G)+2]), "v"(EP[8*(G)+3]), \
          "v"(EP[8*(G)+4]), "v"(EP[8*(G)+5]), "v"(EP[8*(G)+6]), "v"(EP[8*(G)+7]) \
        : SCLOB);

// one step: s_j = sum_i q_i E_ij; exact pow2 rescale; kcum on SALU (uniform)
#define STEP(tc_, EM) { \
    float2 a0, a1, a2, a3; \
    GRP0() GRPN(1) GRPN(2) GRPN(3) \
    const float sdot = ((a0.x + a0.y) + (a1.x + a1.y)) \
                     + ((a2.x + a2.y) + (a3.x + a3.y)); \
    const float s0v = readlane_f(sdot, 0); \
    const int   k   = ((__float_as_int(s0v) >> 23) & 255) - 127; \
    const bool  act = (tc_) <= last; \
    kcum += act ? k : 0; \
    const float qn = (EM) * ldexpf(sdot, -k); \
    q = act ? qn : q; \
}

__global__ __launch_bounds__(64, 1) void crf_kernel(
    const float* __restrict__ inputs,   // B*T*N fp32
    const float* __restrict__ trans,    // N*N fp32
    const int*   __restrict__ tags,     // B*T
    const int*   __restrict__ lens,     // B
    float*       __restrict__ out)      // [0,512) ll, [512,4608) trans copy
{
    const int b = blockIdx.x;
    const int j = threadIdx.x;          // 0..63

    // pass-through output: transition_params (4096 floats over first 64 blocks)
    if (b < 64) out[BB + b * 64 + j] = trans[b * 64 + j];

    const int L    = lens[b];
    const int last = (L - 1) > 0 ? (L - 1) : 0;

    const float* inb  = inputs + (size_t)b * TT * NN;
    const int*   tagb = tags + (size_t)b * TT;

    // ---- sequence score: unary (t < L) + binary (t+1 < L), 64 lanes x 8 ----
    float sc = 0.f;
    #pragma unroll
    for (int k = 0; k < 8; ++k) {
        const int t  = k * 64 + j;
        const int tg = tagb[t];
        if (t < L) sc += inb[t * NN + tg];
        if (t + 1 < L) sc += trans[tg * NN + tagb[t + 1]];   // L<=511 => safe
    }
    #pragma unroll
    for (int x = 32; x >= 1; x >>= 1) sc += __shfl_xor(sc, x, 64);

    // ---- E pairs: EP[g] = {exp(trans[2g][j]), exp(trans[2g+1][j])} ----
    float2 EP[32];
    #pragma unroll
    for (int g = 0; g < 32; ++g) {
        EP[g].x = __expf(trans[(2 * g)     * NN + j]);
        EP[g].y = __expf(trans[(2 * g + 1) * NN + j]);
    }

    // ---- linear-space state: q = exp(alpha - C), C = m0 + kcum*ln2 ----
    const float alpha0 = inb[j];          // t = 0
    const float m0 = readlane_f(alpha0, 0);
    float q = __expf(alpha0 - m0);
    int kcum = 0;

    // emit prefetch: 8-step halves, double-buffered; exp applied AFTER the
    // loads have had 8 steps to land (never stalls on vmcnt at the chain).
    float4 fA0, fA1, fB0, fB1;

#define LD(vec, comp, tt) { const int tc_ = (tt) <= last ? (tt) : last; \
                            vec.comp = inb[tc_ * NN + j]; }
#define LOAD8(v0, v1, base) \
    LD(v0, x, (base) + 0) LD(v0, y, (base) + 1) LD(v0, z, (base) + 2) LD(v0, w, (base) + 3) \
    LD(v1, x, (base) + 4) LD(v1, y, (base) + 5) LD(v1, z, (base) + 6) LD(v1, w, (base) + 7)
#define EXP8(v0, v1) \
    v0.x = __expf(v0.x); v0.y = __expf(v0.y); v0.z = __expf(v0.z); v0.w = __expf(v0.w); \
    v1.x = __expf(v1.x); v1.y = __expf(v1.y); v1.z = __expf(v1.z); v1.w = __expf(v1.w);

    LOAD8(fA0, fA1, 1)
    EXP8(fA0, fA1)

    for (int t0 = 1; t0 <= last; t0 += 16) {
        LOAD8(fB0, fB1, t0 + 8)
        STEP(t0 + 0, fA0.x) STEP(t0 + 1, fA0.y) STEP(t0 + 2, fA0.z) STEP(t0 + 3, fA0.w)
        STEP(t0 + 4, fA1.x) STEP(t0 + 5, fA1.y) STEP(t0 + 6, fA1.z) STEP(t0 + 7, fA1.w)
        EXP8(fB0, fB1)
        LOAD8(fA0, fA1, t0 + 16)
        STEP(t0 + 8,  fB0.x) STEP(t0 + 9,  fB0.y) STEP(t0 + 10, fB0.z) STEP(t0 + 11, fB0.w)
        STEP(t0 + 12, fB1.x) STEP(t0 + 13, fB1.y) STEP(t0 + 14, fB1.z) STEP(t0 + 15, fB1.w)
        EXP8(fA0, fA1)
    }
#undef EXP8
#undef LOAD8
#undef LD

    // ---- lognorm = C + log(sum_j q_j); C exact from integer kcum ----
    float qs = q;
    #pragma unroll
    for (int x = 32; x >= 1; x >>= 1) qs += __shfl_xor(qs, x, 64);
    if (j == 0) {
        const double C = (double)m0 + (double)kcum * 0.6931471805599453;
        out[b] = sc - (float)((double)__logf(qs) + C);
    }
}

extern "C" void kernel_launch(void* const* d_in, const int* in_sizes, int n_in,
                              void* d_out, int out_size, void* d_ws, size_t ws_size,
                              hipStream_t stream) {
    const float* inputs = (const float*)d_in[0];
    const float* trans  = (const float*)d_in[1];
    const int*   tags   = (const int*)d_in[2];
    const int*   lens   = (const int*)d_in[3];
    float*       out    = (float*)d_out;

    crf_kernel<<<dim3(BB), dim3(64), 0, stream>>>(inputs, trans, tags, lens, out);
}

// Round 8
// 202.673 us; speedup vs baseline: 1.1726x; 1.1726x over previous
//
#include <hip/hip_runtime.h>

#define BB 512
#define TT 512
#define NN 64

__device__ __forceinline__ float readlane_f(float v, int lane) {
    return __int_as_float(__builtin_amdgcn_readlane(__float_as_int(v), lane));
}

// R8: cost model (R1-R7): time ~= VALU-slots/step x ~4.5 cyc (per-wave issue
// cadence; independent of deps -- R5; pk ops = 2 slots -- R7). So: cut slots.
// The 64 readlane broadcasts die via DPP row rotations fused into the fmac:
//   s_j = sum_{b,r} q[rot(j,b,r)] * Ed[b][r][j]
// rot = row_ror:r (free, inside v_fmac_f32_dpp) on 4 base copies of q
// (3 ds_bpermute, latency hidden under the b=0 fmac block). Ed is E
// diagonally reordered at prologue so every access is compile-time-named.
// A runtime probe measures the HW's row_ror direction (dhw) and the Ed
// indexing absorbs it -- no rotation-semantics risk. Linear space (R7),
// rescale every 4th step by s_0's exponent (integer-exact kcum); headroom:
// growth < 2^20/step, spread < 2^29 => max exp < 2^107 < fp32 range.

#define S2(x) #x
#define S1(x) S2(x)

#define FMAC_DPP(ACC, QB, EV, R) \
    asm("v_fmac_f32_dpp %0, %1, %2 row_ror:" S1(R) " row_mask:0xf bank_mask:0xf" \
        : "+v"(ACC) : "v"(QB), "v"(EV));
#define MUL_DPP(DST, QB, EV, R) \
    asm("v_mul_f32_dpp %0, %1, %2 row_ror:" S1(R) " row_mask:0xf bank_mask:0xf" \
        : "=v"(DST) : "v"(QB), "v"(EV));

// b=0 block: initializes the 4 accumulator chains (no zero-movs needed)
#define BLK_FIRST(QB, C0, C1, C2, C3) \
    a0 = QB * C0.x; \
    MUL_DPP(a1, QB, C0.y, 1)  MUL_DPP(a2, QB, C0.z, 2)  MUL_DPP(a3, QB, C0.w, 3) \
    FMAC_DPP(a0, QB, C1.x, 4)  FMAC_DPP(a1, QB, C1.y, 5) \
    FMAC_DPP(a2, QB, C1.z, 6)  FMAC_DPP(a3, QB, C1.w, 7) \
    FMAC_DPP(a0, QB, C2.x, 8)  FMAC_DPP(a1, QB, C2.y, 9) \
    FMAC_DPP(a2, QB, C2.z, 10) FMAC_DPP(a3, QB, C2.w, 11) \
    FMAC_DPP(a0, QB, C3.x, 12) FMAC_DPP(a1, QB, C3.y, 13) \
    FMAC_DPP(a2, QB, C3.z, 14) FMAC_DPP(a3, QB, C3.w, 15)

#define BLK(QB, C0, C1, C2, C3) \
    a0 = fmaf(QB, C0.x, a0); \
    FMAC_DPP(a1, QB, C0.y, 1)  FMAC_DPP(a2, QB, C0.z, 2)  FMAC_DPP(a3, QB, C0.w, 3) \
    FMAC_DPP(a0, QB, C1.x, 4)  FMAC_DPP(a1, QB, C1.y, 5) \
    FMAC_DPP(a2, QB, C1.z, 6)  FMAC_DPP(a3, QB, C1.w, 7) \
    FMAC_DPP(a0, QB, C2.x, 8)  FMAC_DPP(a1, QB, C2.y, 9) \
    FMAC_DPP(a2, QB, C2.z, 10) FMAC_DPP(a3, QB, C2.w, 11) \
    FMAC_DPP(a0, QB, C3.x, 12) FMAC_DPP(a1, QB, C3.y, 13) \
    FMAC_DPP(a2, QB, C3.z, 14) FMAC_DPP(a3, QB, C3.w, 15)

// one step; RESC is a compile-time 0/1 (rescale every 4th step)
#define STEP(tc_, EM, RESC) { \
    asm("s_nop 1" : "+v"(q));   /* VALU-write -> DPP-read hazard fence */ \
    const int qi = __float_as_int(q); \
    const float q1 = __int_as_float(__builtin_amdgcn_ds_bpermute(a16, qi)); \
    const float q2 = __int_as_float(__builtin_amdgcn_ds_bpermute(a32, qi)); \
    const float q3 = __int_as_float(__builtin_amdgcn_ds_bpermute(a48, qi)); \
    float a0, a1, a2, a3; \
    BLK_FIRST(q, D00, D01, D02, D03) \
    BLK(q1, D10, D11, D12, D13) \
    BLK(q2, D20, D21, D22, D23) \
    BLK(q3, D30, D31, D32, D33) \
    const float s = (a0 + a1) + (a2 + a3); \
    float qn; \
    if (RESC) { \
        const int sb = __float_as_int(readlane_f(s, 0)); \
        const int kb = ((sb >> 23) & 255) - 127; \
        const float sf = __int_as_float((127 - kb) << 23);  /* 2^-kb */ \
        qn = (s * (EM)) * sf; \
        if ((tc_) <= last) kcum += kb; \
    } else { \
        qn = s * (EM); \
    } \
    q = ((tc_) <= last) ? qn : q; \
}

__global__ __launch_bounds__(64, 1) void crf_kernel(
    const float* __restrict__ inputs,   // B*T*N fp32
    const float* __restrict__ trans,    // N*N fp32
    const int*   __restrict__ tags,     // B*T
    const int*   __restrict__ lens,     // B
    float*       __restrict__ out)      // [0,512) ll, [512,4608) trans copy
{
    const int b = blockIdx.x;
    const int j = threadIdx.x;          // 0..63

    // pass-through output: transition_params (4096 floats over first 64 blocks)
    if (b < 64) out[BB + b * 64 + j] = trans[b * 64 + j];

    const int L    = lens[b];
    const int last = (L - 1) > 0 ? (L - 1) : 0;

    const float* inb  = inputs + (size_t)b * TT * NN;
    const int*   tagb = tags + (size_t)b * TT;

    // ---- sequence score: unary (t < L) + binary (t+1 < L), 64 lanes x 8 ----
    float sc = 0.f;
    #pragma unroll
    for (int k = 0; k < 8; ++k) {
        const int t  = k * 64 + j;
        const int tg = tagb[t];
        if (t < L) sc += inb[t * NN + tg];
        if (t + 1 < L) sc += trans[tg * NN + tagb[t + 1]];   // L<=511 => safe
    }
    #pragma unroll
    for (int x = 32; x >= 1; x >>= 1) sc += __shfl_xor(sc, x, 64);

    // ---- DPP direction probe: dst[j] = src[(j&0x30)|((j+dhw)&15)] ----
    const int pr  = __builtin_amdgcn_update_dpp(0, j, 0x121 /*row_ror:1*/,
                                                0xf, 0xf, false);
    const int r0p = __builtin_amdgcn_readlane(pr, 0);
    const int dhw = (r0p == 1) ? 1 : -1;

    // ---- diagonal E table: Ed[b][r][j] = exp(trans[i][j]),
    //      i = (((j&48)|((j+dhw*r)&15)) + 16b) & 63.  64 named floats. ----
    float4 D00, D01, D02, D03, D10, D11, D12, D13;
    float4 D20, D21, D22, D23, D30, D31, D32, D33;
#define LDD(DST, B, R) { \
    const int rr = (j + dhw * (R)) & 15; \
    const int ii = (((j & 48) | rr) + 16 * (B)) & 63; \
    DST = __expf(trans[ii * NN + j]); }
#define LDD4(V, B, R0) LDD(V.x, B, R0) LDD(V.y, B, (R0)+1) \
                       LDD(V.z, B, (R0)+2) LDD(V.w, B, (R0)+3)
    LDD4(D00, 0, 0) LDD4(D01, 0, 4) LDD4(D02, 0, 8) LDD4(D03, 0, 12)
    LDD4(D10, 1, 0) LDD4(D11, 1, 4) LDD4(D12, 1, 8) LDD4(D13, 1, 12)
    LDD4(D20, 2, 0) LDD4(D21, 2, 4) LDD4(D22, 2, 8) LDD4(D23, 2, 12)
    LDD4(D30, 3, 0) LDD4(D31, 3, 4) LDD4(D32, 3, 8) LDD4(D33, 3, 12)
#undef LDD4
#undef LDD

    // bpermute byte-addresses for the 3 base rotations of q
    const int a16 = ((j + 16) & 63) * 4;
    const int a32 = ((j + 32) & 63) * 4;
    const int a48 = ((j + 48) & 63) * 4;

    // ---- linear-space state: q = exp(alpha - m0 - kcum*ln2) ----
    const float alpha0 = inb[j];            // t = 0
    const float m0 = readlane_f(alpha0, 0);
    float q = __expf(alpha0 - m0);
    int kcum = 0;

    // emit prefetch: 8-step halves, double-buffered; exp off-chain (R7).
    float4 fA0, fA1, fB0, fB1;

#define LD(vec, comp, tt) { const int tc_ = (tt) <= last ? (tt) : last; \
                            vec.comp = inb[tc_ * NN + j]; }
#define LOAD8(v0, v1, base) \
    LD(v0, x, (base) + 0) LD(v0, y, (base) + 1) LD(v0, z, (base) + 2) LD(v0, w, (base) + 3) \
    LD(v1, x, (base) + 4) LD(v1, y, (base) + 5) LD(v1, z, (base) + 6) LD(v1, w, (base) + 7)
#define EXP8(v0, v1) \
    v0.x = __expf(v0.x); v0.y = __expf(v0.y); v0.z = __expf(v0.z); v0.w = __expf(v0.w); \
    v1.x = __expf(v1.x); v1.y = __expf(v1.y); v1.z = __expf(v1.z); v1.w = __expf(v1.w);

    LOAD8(fA0, fA1, 1)
    EXP8(fA0, fA1)

    for (int t0 = 1; t0 <= last; t0 += 16) {
        LOAD8(fB0, fB1, t0 + 8)
        STEP(t0 + 0, fA0.x, 0) STEP(t0 + 1, fA0.y, 0)
        STEP(t0 + 2, fA0.z, 0) STEP(t0 + 3, fA0.w, 1)
        STEP(t0 + 4, fA1.x, 0) STEP(t0 + 5, fA1.y, 0)
        STEP(t0 + 6, fA1.z, 0) STEP(t0 + 7, fA1.w, 1)
        EXP8(fB0, fB1)
        LOAD8(fA0, fA1, t0 + 16)
        STEP(t0 + 8,  fB0.x, 0) STEP(t0 + 9,  fB0.y, 0)
        STEP(t0 + 10, fB0.z, 0) STEP(t0 + 11, fB0.w, 1)
        STEP(t0 + 12, fB1.x, 0) STEP(t0 + 13, fB1.y, 0)
        STEP(t0 + 14, fB1.z, 0) STEP(t0 + 15, fB1.w, 1)
        EXP8(fA0, fA1)
    }
#undef EXP8
#undef LOAD8
#undef LD

    // ---- lognorm = m0 + kcum*ln2 + log(sum_j q_j) ----
    float qs = q;
    #pragma unroll
    for (int x = 32; x >= 1; x >>= 1) qs += __shfl_xor(qs, x, 64);
    if (j == 0) {
        const double C = (double)m0 + (double)kcum * 0.6931471805599453;
        out[b] = sc - (float)((double)__logf(qs) + C);
    }
}

extern "C" void kernel_launch(void* const* d_in, const int* in_sizes, int n_in,
                              void* d_out, int out_size, void* d_ws, size_t ws_size,
                              hipStream_t stream) {
    const float* inputs = (const float*)d_in[0];
    const float* trans  = (const float*)d_in[1];
    const int*   tags   = (const int*)d_in[2];
    const int*   lens   = (const int*)d_in[3];
    float*       out    = (float*)d_out;

    crf_kernel<<<dim3(BB), dim3(64), 0, stream>>>(inputs, trans, tags, lens, out);
}